// Round 1
// baseline (4426.500 us; speedup 1.0000x reference)
//
#include <hip/hip_runtime.h>

// DeepEMD metric: sim GEMM (f16-split MFMA) + kernel-form Sinkhorn fully in LDS.
// One block per (query m, way n) pair; K=exp((sim-1)/eps) resident in LDS (153.7KB).

#define MQ 200
#define WAYS 5
#define SHOTS 5
#define CDIM 640
#define NSP 196            // 14*14
#define NPD 208            // padded to 13*16 for MFMA tiling
#define ITERS 50

#define RCP_EPS_LOG2E 28.853900817779268f   // log2(e)/eps
#define EPS_LN2 0.034657359027997264f       // eps*ln(2)
#define TEMP 12.5f

// workspace layout (float offsets); total ~4.93 MB
#define WS_PROTO 0              // [5][640][196]
#define WS_PP  627200           // pooled_p [5][640]
#define WS_PQ  630400           // pooled_q [200][640]
#define WS_MP  758400           // mean_p [5][196]
#define WS_RP  759380           // rnorm_p [5][196]
#define WS_MQ  760360           // mean_q [200][196]
#define WS_RQ  799560           // rnorm_q [200][196]
#define WS_A   838760           // a marginals [200][5][196]
#define WS_B   1034760          // b marginals [200][5][196]

typedef _Float16 half8 __attribute__((ext_vector_type(8)));
typedef float f32x4 __attribute__((ext_vector_type(4)));

#define PAIR_LDS_BYTES 157616   // 196*196*4 + 5*196*4 + 32

// ---------------- prep: proto (shot mean), pooled_p, per-spatial center/norm stats
__global__ __launch_bounds__(64) void k_proto(const float* __restrict__ x2, float* __restrict__ ws) {
  int wy = blockIdx.x, l = threadIdx.x;
  float* proto = ws + WS_PROTO + wy * CDIM * NSP;
  float sum[4] = {0,0,0,0}, ssq[4] = {0,0,0,0};
  for (int c = 0; c < CDIM; c++) {
    float tot = 0.f;
    #pragma unroll
    for (int r = 0; r < 4; r++) {
      int s = l + 64 * r;
      if (s < NSP) {
        float p = 0.f;
        #pragma unroll
        for (int sh = 0; sh < SHOTS; sh++)
          p += x2[((wy * SHOTS + sh) * CDIM + c) * NSP + s];
        p *= 0.2f;
        proto[c * NSP + s] = p;
        sum[r] += p; ssq[r] += p * p; tot += p;
      }
    }
    #pragma unroll
    for (int off = 32; off >= 1; off >>= 1) tot += __shfl_xor(tot, off);
    if (l == 0) ws[WS_PP + wy * CDIM + c] = tot * (1.f / 196.f);
  }
  #pragma unroll
  for (int r = 0; r < 4; r++) {
    int s = l + 64 * r;
    if (s < NSP) {
      float mean = sum[r] * (1.f / 640.f);
      float var = ssq[r] - 640.f * mean * mean;
      ws[WS_MP + wy * NSP + s] = mean;
      ws[WS_RP + wy * NSP + s] = 1.f / fmaxf(sqrtf(fmaxf(var, 0.f)), 1e-8f);
    }
  }
}

// ---------------- prep: pooled_q + query center/norm stats
__global__ __launch_bounds__(64) void k_query(const float* __restrict__ x1, float* __restrict__ ws) {
  int m = blockIdx.x, l = threadIdx.x;
  const float* q = x1 + m * CDIM * NSP;
  float sum[4] = {0,0,0,0}, ssq[4] = {0,0,0,0};
  for (int c = 0; c < CDIM; c++) {
    float tot = 0.f;
    #pragma unroll
    for (int r = 0; r < 4; r++) {
      int s = l + 64 * r;
      if (s < NSP) {
        float p = q[c * NSP + s];
        sum[r] += p; ssq[r] += p * p; tot += p;
      }
    }
    #pragma unroll
    for (int off = 32; off >= 1; off >>= 1) tot += __shfl_xor(tot, off);
    if (l == 0) ws[WS_PQ + m * CDIM + c] = tot * (1.f / 196.f);
  }
  #pragma unroll
  for (int r = 0; r < 4; r++) {
    int s = l + 64 * r;
    if (s < NSP) {
      float mean = sum[r] * (1.f / 640.f);
      float var = ssq[r] - 640.f * mean * mean;
      ws[WS_MQ + m * NSP + s] = mean;
      ws[WS_RQ + m * NSP + s] = 1.f / fmaxf(sqrtf(fmaxf(var, 0.f)), 1e-8f);
    }
  }
}

// ---------------- prep: query-side marginals a[m][n][s]
__global__ __launch_bounds__(256) void k_w1(const float* __restrict__ x1, float* __restrict__ ws) {
  __shared__ float pp[WAYS * CDIM];
  __shared__ float red[256];
  int m = blockIdx.x, t = threadIdx.x;
  for (int i = t; i < WAYS * CDIM; i += 256) pp[i] = ws[WS_PP + i];
  __syncthreads();
  float acc[WAYS] = {0,0,0,0,0};
  const float* q = x1 + m * CDIM * NSP;
  if (t < NSP) {
    for (int c = 0; c < CDIM; c++) {
      float qv = q[c * NSP + t];
      #pragma unroll
      for (int n = 0; n < WAYS; n++) acc[n] += qv * pp[n * CDIM + c];
    }
  }
  #pragma unroll
  for (int n = 0; n < WAYS; n++) {
    float wv = (t < NSP) ? (fmaxf(acc[n], 0.f) + 1e-3f) : 0.f;
    red[t] = wv;
    __syncthreads();
    for (int st = 128; st >= 1; st >>= 1) {
      if (t < st) red[t] += red[t + st];
      __syncthreads();
    }
    float sm = red[0];
    __syncthreads();
    if (t < NSP) ws[WS_A + (m * WAYS + n) * NSP + t] = wv / sm;
  }
}

// ---------------- prep: proto-side marginals b[m][n][s] (already transposed to [m][n][s])
__global__ __launch_bounds__(256) void k_w2(float* __restrict__ ws) {
  __shared__ float pq[CDIM];
  __shared__ float red[256];
  int m = blockIdx.x, t = threadIdx.x;
  for (int i = t; i < CDIM; i += 256) pq[i] = ws[WS_PQ + m * CDIM + i];
  __syncthreads();
  float acc[WAYS] = {0,0,0,0,0};
  if (t < NSP) {
    #pragma unroll
    for (int n = 0; n < WAYS; n++) {
      float a = 0.f;
      for (int c = 0; c < CDIM; c++)
        a += ws[WS_PROTO + (n * CDIM + c) * NSP + t] * pq[c];
      acc[n] = a;
    }
  }
  #pragma unroll
  for (int n = 0; n < WAYS; n++) {
    float wv = (t < NSP) ? (fmaxf(acc[n], 0.f) + 1e-3f) : 0.f;
    red[t] = wv;
    __syncthreads();
    for (int st = 128; st >= 1; st >>= 1) {
      if (t < st) red[t] += red[t + st];
      __syncthreads();
    }
    float sm = red[0];
    __syncthreads();
    if (t < NSP) ws[WS_B + (m * WAYS + n) * NSP + t] = wv / sm;
  }
}

// ---------------- fused pair kernel: GEMM (f16 split) -> K in LDS -> Sinkhorn -> logits
__global__ __launch_bounds__(512, 2) void k_pair(const float* __restrict__ x1,
                                                 const float* __restrict__ ws,
                                                 float* __restrict__ out) {
  extern __shared__ char smem[];
  float* Km  = (float*)smem;                       // [196][196]  (153664 B)
  float* u_l = (float*)(smem + 153664);
  float* v_l = u_l + NSP;
  float* a_l = v_l + NSP;
  float* b_l = a_l + NSP;
  float* cs_l = b_l + NSP;
  float* red = cs_l + NSP;                         // 8 floats

  // GEMM-phase staging (time-multiplexed with Km region; Km written only after GEMM)
  _Float16* Ah = (_Float16*)smem;                  // [4 kgrp][208][8]  13312 B
  _Float16* Al = Ah + 4 * NPD * 8;
  _Float16* Bh = Al + 4 * NPD * 8;
  _Float16* Bl = Bh + 4 * NPD * 8;
  float* mq = (float*)(Bl + 4 * NPD * 8);          // [208] each, ends @ 56576 B
  float* rq = mq + NPD;
  float* mp = rq + NPD;
  float* rp = mp + NPD;

  int p = blockIdx.x, m = p / WAYS, n = p % WAYS;
  int t = threadIdx.x, w = t >> 6, l = t & 63;

  // ---- P0: stage stats + marginals, init v=1, colsum=0
  for (int s = t; s < NPD; s += 512) {
    bool ok = s < NSP;
    mq[s] = ok ? ws[WS_MQ + m * NSP + s] : 0.f;
    rq[s] = ok ? ws[WS_RQ + m * NSP + s] : 0.f;
    mp[s] = ok ? ws[WS_MP + n * NSP + s] : 0.f;
    rp[s] = ok ? ws[WS_RP + n * NSP + s] : 0.f;
    if (ok) {
      a_l[s] = ws[WS_A + (m * WAYS + n) * NSP + s];
      b_l[s] = ws[WS_B + (m * WAYS + n) * NSP + s];
      v_l[s] = 1.f;
      cs_l[s] = 0.f;
    }
  }
  __syncthreads();

  // ---- P1: sim = qn . pn^T via mfma_f32_16x16x32_f16 with hi/lo split (3 passes)
  // wave w owns output tile-col w (and w+8 if w<5); 13 row-tiles each.
  f32x4 acc0[13], acc1[13];
  #pragma unroll
  for (int i = 0; i < 13; i++) {
    #pragma unroll
    for (int r = 0; r < 4; r++) { acc0[i][r] = 0.f; acc1[i][r] = 0.f; }
  }

  const float* qb = x1 + m * CDIM * NSP;
  const float* pb = ws + WS_PROTO + n * CDIM * NSP;

  for (int kc = 0; kc < CDIM / 32; kc++) {
    int c0 = kc * 32;
    // stage: slot = (mat, kgrp, s); each slot loads 8 channels, coalesced along s
    for (int slot = t; slot < 2 * 4 * NPD; slot += 512) {
      int s = slot % NPD;
      int rest = slot / NPD;         // 0..7
      int kg = rest & 3, mat = rest >> 2;
      const float* src = mat ? pb : qb;
      float mean = mat ? mp[s] : mq[s];
      float rn   = mat ? rp[s] : rq[s];
      half8 hv, lv;
      #pragma unroll
      for (int qq = 0; qq < 8; qq++) {
        float x = 0.f;
        if (s < NSP) x = (src[(c0 + kg * 8 + qq) * NSP + s] - mean) * rn;
        _Float16 h = (_Float16)x;
        _Float16 lo = (_Float16)(x - (float)h);
        hv[qq] = h; lv[qq] = lo;
      }
      _Float16* dh = mat ? Bh : Ah;
      _Float16* dl = mat ? Bl : Al;
      *(half8*)&dh[(kg * NPD + s) * 8] = hv;
      *(half8*)&dl[(kg * NPD + s) * 8] = lv;
    }
    __syncthreads();

    {
      int lid = l & 15, kg = l >> 4;
      int ro = kg * NPD;
      half8 b0h = *(const half8*)&Bh[(ro + w * 16 + lid) * 8];
      half8 b0l = *(const half8*)&Bl[(ro + w * 16 + lid) * 8];
      half8 b1h{}, b1l{};
      if (w < 5) {
        b1h = *(const half8*)&Bh[(ro + (w + 8) * 16 + lid) * 8];
        b1l = *(const half8*)&Bl[(ro + (w + 8) * 16 + lid) * 8];
      }
      #pragma unroll
      for (int tt = 0; tt < 13; tt++) {
        half8 ah = *(const half8*)&Ah[(ro + tt * 16 + lid) * 8];
        half8 al = *(const half8*)&Al[(ro + tt * 16 + lid) * 8];
        acc0[tt] = __builtin_amdgcn_mfma_f32_16x16x32_f16(ah, b0h, acc0[tt], 0, 0, 0);
        acc0[tt] = __builtin_amdgcn_mfma_f32_16x16x32_f16(ah, b0l, acc0[tt], 0, 0, 0);
        acc0[tt] = __builtin_amdgcn_mfma_f32_16x16x32_f16(al, b0h, acc0[tt], 0, 0, 0);
        if (w < 5) {
          acc1[tt] = __builtin_amdgcn_mfma_f32_16x16x32_f16(ah, b1h, acc1[tt], 0, 0, 0);
          acc1[tt] = __builtin_amdgcn_mfma_f32_16x16x32_f16(ah, b1l, acc1[tt], 0, 0, 0);
          acc1[tt] = __builtin_amdgcn_mfma_f32_16x16x32_f16(al, b1h, acc1[tt], 0, 0, 0);
        }
      }
    }
    __syncthreads();
  }

  // ---- P2: K = exp((sim-1)/eps) into LDS (clobbers staging area, which is dead)
  {
    int lid = l & 15, kg = l >> 4;
    #pragma unroll
    for (int cc = 0; cc < 2; cc++) {
      if (cc == 1 && w >= 5) continue;
      int j = (cc ? (w + 8) : w) * 16 + lid;
      if (j < NSP) {
        #pragma unroll
        for (int tt = 0; tt < 13; tt++) {
          #pragma unroll
          for (int r = 0; r < 4; r++) {
            int i = tt * 16 + kg * 4 + r;   // C/D layout: col=lane&15, row=(lane>>4)*4+reg
            if (i < NSP) {
              float sv = cc ? acc1[tt][r] : acc0[tt][r];
              Km[i * NSP + j] = exp2f((sv - 1.f) * RCP_EPS_LOG2E);
            }
          }
        }
      }
    }
  }
  __syncthreads();

  // ---- P3: Sinkhorn, kernel form: u = a/(K v); v = b/(K^T u); 50 iters
  for (int it = 0; it < ITERS; it++) {
    // row pass
    if (t < NSP) {
      float r = 0.f;
      for (int jb = 0; jb < 49; jb++) {
        f32x4 k4 = *(const f32x4*)&Km[t * NSP + jb * 4];
        f32x4 v4 = *(const f32x4*)&v_l[jb * 4];
        r += k4[0] * v4[0] + k4[1] * v4[1] + k4[2] * v4[2] + k4[3] * v4[3];
      }
      u_l[t] = a_l[t] / fmaxf(r, 1e-35f);
    }
    __syncthreads();
    // column pass: per-wave row-major accumulation + LDS atomic combine
    {
      float c0v = 0.f, c1v = 0.f, c2v = 0.f, c3v = 0.f;
      int jj = l * 4;
      for (int i = w; i < NSP; i += 8) {
        float ui = u_l[i];
        if (jj < NSP) {
          f32x4 k4 = *(const f32x4*)&Km[i * NSP + jj];
          c0v += k4[0] * ui; c1v += k4[1] * ui; c2v += k4[2] * ui; c3v += k4[3] * ui;
        }
      }
      if (jj < NSP) {
        atomicAdd(&cs_l[jj + 0], c0v);
        atomicAdd(&cs_l[jj + 1], c1v);
        atomicAdd(&cs_l[jj + 2], c2v);
        atomicAdd(&cs_l[jj + 3], c3v);
      }
    }
    __syncthreads();
    if (t < NSP) {
      float cs = cs_l[t];
      v_l[t] = b_l[t] / fmaxf(cs, 1e-35f);
      cs_l[t] = 0.f;
    }
    __syncthreads();
  }

  // ---- P4: logits = temp * sum_ij sim * u_i K_ij v_j, sim recovered via log2(K)
  float rowv = 0.f;
  if (t < NSP) {
    float s = 0.f;
    for (int jb = 0; jb < 49; jb++) {
      f32x4 k4 = *(const f32x4*)&Km[t * NSP + jb * 4];
      f32x4 v4 = *(const f32x4*)&v_l[jb * 4];
      #pragma unroll
      for (int qq = 0; qq < 4; qq++) {
        float kk = k4[qq];
        float sim = 1.f + EPS_LN2 * log2f(kk);
        s += sim * kk * v4[qq];
      }
    }
    rowv = u_l[t] * s;
  }
  if (w < 4) {
    #pragma unroll
    for (int off = 32; off >= 1; off >>= 1) rowv += __shfl_down(rowv, off);
    if (l == 0) red[w] = rowv;
  }
  __syncthreads();
  if (t == 0) out[p] = TEMP * (red[0] + red[1] + red[2] + red[3]);
}

extern "C" void kernel_launch(void* const* d_in, const int* in_sizes, int n_in,
                              void* d_out, int out_size, void* d_ws, size_t ws_size,
                              hipStream_t stream) {
  const float* x1 = (const float*)d_in[0];   // [200][640][196]
  const float* x2 = (const float*)d_in[1];   // [25][640][196]
  float* ws = (float*)d_ws;                  // needs ~4.93 MB
  float* out = (float*)d_out;                // [200][5] f32

  hipLaunchKernelGGL(k_proto, dim3(WAYS), dim3(64), 0, stream, x2, ws);
  hipLaunchKernelGGL(k_query, dim3(MQ), dim3(64), 0, stream, x1, ws);
  hipLaunchKernelGGL(k_w1, dim3(MQ), dim3(256), 0, stream, x1, ws);
  hipLaunchKernelGGL(k_w2, dim3(MQ), dim3(256), 0, stream, ws);
  hipLaunchKernelGGL(k_pair, dim3(MQ * WAYS), dim3(512), PAIR_LDS_BYTES, stream, x1, ws, out);
}

// Round 2
// 1874.784 us; speedup vs baseline: 2.3611x; 2.3611x over previous
//
#include <hip/hip_runtime.h>

// DeepEMD metric, round 2: parallel prep + precomputed f16-split operands +
// 1024-thread fused pair kernel (GEMM dbuf staging -> K in LDS -> Sinkhorn).

#define MQ 200
#define WAYS 5
#define SHOTS 5
#define CDIM 640
#define NSP 196
#define SPAD 208
#define ITERS 50

#define RCP_EPS_LOG2E 28.853900817779268f   // log2(e)/eps
#define EPS_LN2 0.034657359027997264f       // eps*ln(2)
#define TEMP 12.5f

// ---- workspace byte offsets ----
#define B_PF32 0u           // proto f32 [5][640][196]
#define B_PP   2508800u     // pooled_p [5][640]
#define B_PQ   2521600u     // pooled_q [200][640]
#define B_SP   3033600u     // accum: sum_p [5][196]
#define B_SP2  3037520u
#define B_SQ   3041440u     // accum: sum_q [200][196]
#define B_SQ2  3198240u
#define B_MP   3355040u
#define B_RP   3358960u
#define B_MQ   3362880u
#define B_RQ   3519680u
#define B_A    3676480u     // a marginals [200][5][196]
#define B_B    4460480u     // b marginals [200][5][196]
#define B_PF16 5244480u     // proto f16 staged [5][20][26624B]
#define B_QF16 7906880u     // query f16 staged [200][20][26624B]
#define KCB    26624u       // bytes per (row,kc) block: hi 13312 + lo 13312
#define ROWB   532480u      // 20*KCB
#define WS_NEED_QPRE 114402880ull

typedef _Float16 half8 __attribute__((ext_vector_type(8)));
typedef float f32x4 __attribute__((ext_vector_type(4)));

#define PAIR_LDS 163088     // Km 153664 + u/v/a/b 3136 + csp 6272 + red 16

// ---------------- proto: shot-mean, pooled_p, channel-sum partials ----------------
__global__ __launch_bounds__(256) void k_proto(const float* __restrict__ x2, char* __restrict__ wsb) {
  float* pf32 = (float*)(wsb + B_PF32);
  float* pp   = (float*)(wsb + B_PP);
  float* sp   = (float*)(wsb + B_SP);
  float* sp2  = (float*)(wsb + B_SP2);
  __shared__ float ppl[64];
  int cg = blockIdx.x, wy = blockIdx.y, t = threadIdx.x, l = t & 63;
  if (t < 64) ppl[t] = 0.f;
  __syncthreads();
  int s = t; bool act = s < NSP;
  float as_ = 0.f, as2 = 0.f;
  int cb = cg * 64;
  for (int c = 0; c < 64; c++) {
    float p = 0.f;
    if (act) {
      const float* b0 = x2 + ((size_t)(wy * SHOTS) * CDIM + (cb + c)) * NSP + s;
      #pragma unroll
      for (int sh = 0; sh < SHOTS; sh++) p += b0[(size_t)sh * CDIM * NSP];
      p *= 0.2f;
      pf32[((size_t)wy * CDIM + cb + c) * NSP + s] = p;
      as_ += p; as2 += p * p;
    }
    float ps = p;
    #pragma unroll
    for (int off = 32; off >= 1; off >>= 1) ps += __shfl_xor(ps, off);
    if (l == 0) atomicAdd(&ppl[c], ps);
  }
  __syncthreads();
  if (act) { atomicAdd(&sp[wy * NSP + s], as_); atomicAdd(&sp2[wy * NSP + s], as2); }
  if (t < 64) pp[wy * CDIM + cb + t] = ppl[t] * (1.f / 196.f);
}

// ---------------- query: pooled_q, channel-sum partials ----------------
__global__ __launch_bounds__(256) void k_qstats(const float* __restrict__ x1, char* __restrict__ wsb) {
  float* pq  = (float*)(wsb + B_PQ);
  float* sq  = (float*)(wsb + B_SQ);
  float* sq2 = (float*)(wsb + B_SQ2);
  __shared__ float ppl[64];
  int cg = blockIdx.x, m = blockIdx.y, t = threadIdx.x, l = t & 63;
  if (t < 64) ppl[t] = 0.f;
  __syncthreads();
  int s = t; bool act = s < NSP;
  float as_ = 0.f, as2 = 0.f;
  int cb = cg * 64;
  const float* xb = x1 + (size_t)m * CDIM * NSP;
  for (int c = 0; c < 64; c++) {
    float p = 0.f;
    if (act) { p = xb[(size_t)(cb + c) * NSP + s]; as_ += p; as2 += p * p; }
    float ps = p;
    #pragma unroll
    for (int off = 32; off >= 1; off >>= 1) ps += __shfl_xor(ps, off);
    if (l == 0) atomicAdd(&ppl[c], ps);
  }
  __syncthreads();
  if (act) { atomicAdd(&sq[(size_t)m * NSP + s], as_); atomicAdd(&sq2[(size_t)m * NSP + s], as2); }
  if (t < 64) pq[(size_t)m * CDIM + cb + t] = ppl[t] * (1.f / 196.f);
}

// ---------------- finalize center/norm stats ----------------
__global__ __launch_bounds__(256) void k_fin(char* __restrict__ wsb) {
  int i = blockIdx.x * 256 + threadIdx.x;
  if (i < WAYS * NSP) {
    float sm = ((float*)(wsb + B_SP))[i], s2 = ((float*)(wsb + B_SP2))[i];
    float mean = sm * (1.f / CDIM);
    float var = s2 - CDIM * mean * mean;
    ((float*)(wsb + B_MP))[i] = mean;
    ((float*)(wsb + B_RP))[i] = 1.f / fmaxf(sqrtf(fmaxf(var, 0.f)), 1e-8f);
  } else if (i < WAYS * NSP + MQ * NSP) {
    int j = i - WAYS * NSP;
    float sm = ((float*)(wsb + B_SQ))[j], s2 = ((float*)(wsb + B_SQ2))[j];
    float mean = sm * (1.f / CDIM);
    float var = s2 - CDIM * mean * mean;
    ((float*)(wsb + B_MQ))[j] = mean;
    ((float*)(wsb + B_RQ))[j] = 1.f / fmaxf(sqrtf(fmaxf(var, 0.f)), 1e-8f);
  }
}

// ---------------- center+normalize -> f16 hi/lo in MFMA staging layout ----------------
__global__ __launch_bounds__(256) void k_conv(const float* __restrict__ src,
                                              const float* __restrict__ meanA,
                                              const float* __restrict__ rnA,
                                              char* __restrict__ dst) {
  int kc = blockIdx.x, rI = blockIdx.y, t = threadIdx.x;
  const float* s0 = src + (size_t)rI * CDIM * NSP;
  const float* me = meanA + (size_t)rI * NSP;
  const float* rn = rnA + (size_t)rI * NSP;
  _Float16* d = (_Float16*)(dst + (size_t)rI * ROWB + (size_t)kc * KCB);
  int s = t;
  if (s < SPAD) {
    bool ok = s < NSP;
    float mm = ok ? me[s] : 0.f, rr = ok ? rn[s] : 0.f;
    for (int kg = 0; kg < 4; kg++) {
      half8 hv{}, lv{};
      #pragma unroll
      for (int qq = 0; qq < 8; qq++) {
        float x = 0.f;
        if (ok) x = (s0[(size_t)(kc * 32 + kg * 8 + qq) * NSP + s] - mm) * rr;
        _Float16 h = (_Float16)x;
        hv[qq] = h; lv[qq] = (_Float16)(x - (float)h);
      }
      *(half8*)&d[(kg * SPAD + s) * 8] = hv;
      *(half8*)&d[6656 + (kg * SPAD + s) * 8] = lv;
    }
  }
}

// ---------------- query-side marginals ----------------
__global__ __launch_bounds__(256) void k_w1(const float* __restrict__ x1, char* __restrict__ wsb) {
  const float* pp = (const float*)(wsb + B_PP);
  float* A = (float*)(wsb + B_A);
  __shared__ float ppl[WAYS * CDIM];
  __shared__ float red[256];
  int m = blockIdx.x, t = threadIdx.x;
  for (int i = t; i < WAYS * CDIM; i += 256) ppl[i] = pp[i];
  __syncthreads();
  float acc[WAYS] = {0, 0, 0, 0, 0};
  const float* q = x1 + (size_t)m * CDIM * NSP;
  if (t < NSP) {
    for (int c = 0; c < CDIM; c++) {
      float qv = q[(size_t)c * NSP + t];
      #pragma unroll
      for (int n = 0; n < WAYS; n++) acc[n] += qv * ppl[n * CDIM + c];
    }
  }
  #pragma unroll
  for (int n = 0; n < WAYS; n++) {
    float wv = (t < NSP) ? (fmaxf(acc[n], 0.f) + 1e-3f) : 0.f;
    red[t] = wv;
    __syncthreads();
    for (int st = 128; st >= 1; st >>= 1) { if (t < st) red[t] += red[t + st]; __syncthreads(); }
    float sm = red[0];
    __syncthreads();
    if (t < NSP) A[((size_t)m * WAYS + n) * NSP + t] = wv / sm;
  }
}

// ---------------- proto-side marginals ----------------
__global__ __launch_bounds__(256) void k_w2(char* __restrict__ wsb) {
  const float* pf32 = (const float*)(wsb + B_PF32);
  const float* pq = (const float*)(wsb + B_PQ);
  float* B = (float*)(wsb + B_B);
  __shared__ float pql[CDIM];
  __shared__ float red[256];
  int m = blockIdx.x, t = threadIdx.x;
  for (int i = t; i < CDIM; i += 256) pql[i] = pq[(size_t)m * CDIM + i];
  __syncthreads();
  float acc[WAYS] = {0, 0, 0, 0, 0};
  if (t < NSP) {
    #pragma unroll
    for (int n = 0; n < WAYS; n++) {
      float a = 0.f;
      for (int c = 0; c < CDIM; c++) a += pf32[((size_t)n * CDIM + c) * NSP + t] * pql[c];
      acc[n] = a;
    }
  }
  #pragma unroll
  for (int n = 0; n < WAYS; n++) {
    float wv = (t < NSP) ? (fmaxf(acc[n], 0.f) + 1e-3f) : 0.f;
    red[t] = wv;
    __syncthreads();
    for (int st = 128; st >= 1; st >>= 1) { if (t < st) red[t] += red[t + st]; __syncthreads(); }
    float sm = red[0];
    __syncthreads();
    if (t < NSP) B[((size_t)m * WAYS + n) * NSP + t] = wv / sm;
  }
}

#define MFMA16(a, b, c) __builtin_amdgcn_mfma_f32_16x16x32_f16(a, b, c, 0, 0, 0)

// ---------------- fused pair kernel ----------------
template <bool QPRE>
__global__ __launch_bounds__(1024) void k_pair(const float* __restrict__ x1,
                                               char* __restrict__ wsb,
                                               float* __restrict__ out) {
  extern __shared__ char smem[];
  float* Km = (float*)smem;                    // [196][196]
  float* u_l = (float*)(smem + 153664);
  float* v_l = u_l + NSP;
  float* a_l = v_l + NSP;
  float* b_l = a_l + NSP;
  float* csp = (float*)(smem + 156800);        // [8][196]
  float* red = (float*)(smem + 163072);        // 4 floats
  float* mqs = csp;                            // !QPRE: stats staging (GEMM phase only)
  float* rqs = csp + SPAD;

  int p = blockIdx.x, m = p / WAYS, n = p % WAYS;
  int t = threadIdx.x, w = t >> 6, l = t & 63;
  int lid = l & 15, kg4 = l >> 4;
  int WR = w >> 2, WC = w & 3;

  // P0
  if (t < NSP) {
    a_l[t] = ((const float*)(wsb + B_A))[((size_t)m * WAYS + n) * NSP + t];
    b_l[t] = ((const float*)(wsb + B_B))[((size_t)m * WAYS + n) * NSP + t];
    v_l[t] = 1.f;
  }
  if (!QPRE) {
    if (t < SPAD) {
      bool ok = t < NSP;
      mqs[t] = ok ? ((const float*)(wsb + B_MQ))[(size_t)m * NSP + t] : 0.f;
      rqs[t] = ok ? ((const float*)(wsb + B_RQ))[(size_t)m * NSP + t] : 0.f;
    }
  }
  __syncthreads();

  const char* srcQ = wsb + B_QF16 + (size_t)m * ROWB;
  const char* srcP = wsb + B_PF16 + (size_t)n * ROWB;

  f32x4 acc[4][4];
  #pragma unroll
  for (int qi = 0; qi < 4; qi++)
    #pragma unroll
    for (int r = 0; r < 4; r++)
      #pragma unroll
      for (int e = 0; e < 4; e++) acc[qi][r][e] = 0.f;

  f32x4 st0, st1, st2, st3;

  auto STAGE_LOAD = [&](int kc) {
    if constexpr (QPRE) {
      const char* q0 = srcQ + (size_t)kc * KCB;
      const char* p0 = srcP + (size_t)kc * KCB;
      st0 = *(const f32x4*)(q0 + (size_t)t * 16);
      st1 = (t < 640) ? *(const f32x4*)(q0 + (size_t)(1024 + t) * 16)
                      : *(const f32x4*)(p0 + (size_t)(t - 640) * 16);
      st2 = *(const f32x4*)(p0 + (size_t)(384 + t) * 16);
      if (t < 256) st3 = *(const f32x4*)(p0 + (size_t)(1408 + t) * 16);
    } else {
      int kg = t >> 8, s = t & 255;
      half8 hv{}, lv{};
      if (s < SPAD) {
        bool ok = s < NSP;
        float mm = mqs[s], rr = rqs[s];
        #pragma unroll
        for (int qq = 0; qq < 8; qq++) {
          float x = 0.f;
          if (ok) x = (x1[((size_t)m * CDIM + kc * 32 + kg * 8 + qq) * NSP + s] - mm) * rr;
          _Float16 h = (_Float16)x;
          hv[qq] = h; lv[qq] = (_Float16)(x - (float)h);
        }
      }
      st0 = __builtin_bit_cast(f32x4, hv);
      st1 = __builtin_bit_cast(f32x4, lv);
      const char* p0 = srcP + (size_t)kc * KCB;
      st2 = *(const f32x4*)(p0 + (size_t)t * 16);
      if (t < 640) st3 = *(const f32x4*)(p0 + (size_t)(1024 + t) * 16);
    }
  };
  auto STAGE_WRITE = [&](char* bufc) {
    if constexpr (QPRE) {
      *(f32x4*)(bufc + (size_t)t * 16) = st0;
      *(f32x4*)(bufc + (size_t)(1024 + t) * 16) = st1;
      *(f32x4*)(bufc + (size_t)(2048 + t) * 16) = st2;
      if (t < 256) *(f32x4*)(bufc + (size_t)(3072 + t) * 16) = st3;
    } else {
      int kg = t >> 8, s = t & 255;
      if (s < SPAD) {
        *(f32x4*)(bufc + (size_t)(kg * SPAD + s) * 16) = st0;
        *(f32x4*)(bufc + 13312 + (size_t)(kg * SPAD + s) * 16) = st1;
      }
      *(f32x4*)(bufc + 26624 + (size_t)t * 16) = st2;
      if (t < 640) *(f32x4*)(bufc + 26624 + (size_t)(1024 + t) * 16) = st3;
    }
  };

  // ---- GEMM: 20 K-chunks, double-buffered staging, 1 barrier per chunk
  int buf = 0;
  STAGE_LOAD(0);
  STAGE_WRITE(smem);
  __syncthreads();
  for (int kc = 0; kc < 20; kc++) {
    char* cur = smem + (size_t)buf * 53248;
    char* nxt = smem + (size_t)(buf ^ 1) * 53248;
    if (kc < 19) STAGE_LOAD(kc + 1);
    const _Float16* Ah = (const _Float16*)cur;
    const _Float16* Al = (const _Float16*)(cur + 13312);
    const _Float16* Bh = (const _Float16*)(cur + 26624);
    const _Float16* Bl = (const _Float16*)(cur + 39936);
    half8 ah[4], al[4];
    #pragma unroll
    for (int qi = 0; qi < 4; qi++) {
      int tt = WR + 4 * qi;
      if (tt < 13) {
        ah[qi] = *(const half8*)&Ah[((size_t)kg4 * SPAD + tt * 16 + lid) * 8];
        al[qi] = *(const half8*)&Al[((size_t)kg4 * SPAD + tt * 16 + lid) * 8];
      }
    }
    #pragma unroll
    for (int r = 0; r < 4; r++) {
      int jt = WC + 4 * r;
      if (jt < 13) {
        half8 bh = *(const half8*)&Bh[((size_t)kg4 * SPAD + jt * 16 + lid) * 8];
        half8 bl = *(const half8*)&Bl[((size_t)kg4 * SPAD + jt * 16 + lid) * 8];
        #pragma unroll
        for (int qi = 0; qi < 4; qi++) {
          int tt = WR + 4 * qi;
          if (tt < 13) {
            acc[qi][r] = MFMA16(ah[qi], bh, acc[qi][r]);
            acc[qi][r] = MFMA16(ah[qi], bl, acc[qi][r]);
            acc[qi][r] = MFMA16(al[qi], bh, acc[qi][r]);
          }
        }
      }
    }
    if (kc < 19) STAGE_WRITE(nxt);
    __syncthreads();
    buf ^= 1;
  }

  // ---- P2: K = exp((sim-1)/eps) into LDS
  #pragma unroll
  for (int qi = 0; qi < 4; qi++) {
    int tt = WR + 4 * qi;
    if (tt < 13) {
      #pragma unroll
      for (int r = 0; r < 4; r++) {
        int jt = WC + 4 * r;
        if (jt < 13) {
          int j = jt * 16 + lid;
          if (j < NSP) {
            #pragma unroll
            for (int e = 0; e < 4; e++) {
              int i = tt * 16 + kg4 * 4 + e;
              if (i < NSP) Km[(size_t)i * NSP + j] = exp2f((acc[qi][r][e] - 1.f) * RCP_EPS_LOG2E);
            }
          }
        }
      }
    }
  }
  __syncthreads();

  // ---- P3: Sinkhorn kernel form, 50 iters
  for (int it = 0; it < ITERS; it++) {
    if (t < 784) {            // row pass: 4 lanes per row
      int rr = t >> 2, h = t & 3;
      float rs = 0.f;
      for (int jb = h; jb < 49; jb += 4) {
        f32x4 k4 = *(const f32x4*)&Km[(size_t)rr * NSP + jb * 4];
        f32x4 v4 = *(const f32x4*)&v_l[jb * 4];
        rs += k4[0] * v4[0] + k4[1] * v4[1] + k4[2] * v4[2] + k4[3] * v4[3];
      }
      rs += __shfl_xor(rs, 1);
      rs += __shfl_xor(rs, 2);
      if (h == 0) u_l[rr] = a_l[rr] / fmaxf(rs, 1e-35f);
    } else {                  // tail threads zero csp for this iteration
      int z = t - 784;
      for (int zz = z; zz < 392; zz += 240) ((f32x4*)csp)[zz] = f32x4{0.f, 0.f, 0.f, 0.f};
    }
    __syncthreads();
    {
      int jj = l * 4;
      if (jj < NSP) {         // col pass: 16 waves, rows strided 16
        float c0 = 0, c1 = 0, c2 = 0, c3 = 0;
        for (int i = w; i < NSP; i += 16) {
          float ui = u_l[i];
          f32x4 k4 = *(const f32x4*)&Km[(size_t)i * NSP + jj];
          c0 += k4[0] * ui; c1 += k4[1] * ui; c2 += k4[2] * ui; c3 += k4[3] * ui;
        }
        float* d = &csp[(size_t)(w & 7) * NSP + jj];
        atomicAdd(d, c0); atomicAdd(d + 1, c1); atomicAdd(d + 2, c2); atomicAdd(d + 3, c3);
      }
    }
    __syncthreads();
    if (t < NSP) {
      float cs = 0.f;
      #pragma unroll
      for (int q8 = 0; q8 < 8; q8++) cs += csp[q8 * NSP + t];
      v_l[t] = b_l[t] / fmaxf(cs, 1e-35f);
    }
    __syncthreads();
  }

  // ---- P4: logits = temp * sum_ij sim * u_i K_ij v_j (sim from log2(K))
  if (t < 784) {
    int rr = t >> 2, h = t & 3;
    float s4 = 0.f;
    for (int jb = h; jb < 49; jb += 4) {
      f32x4 k4 = *(const f32x4*)&Km[(size_t)rr * NSP + jb * 4];
      f32x4 v4 = *(const f32x4*)&v_l[jb * 4];
      #pragma unroll
      for (int qq = 0; qq < 4; qq++) {
        float kk = k4[qq];
        float sim = 1.f + EPS_LN2 * log2f(kk);
        s4 += sim * kk * v4[qq];
      }
    }
    s4 += __shfl_xor(s4, 1);
    s4 += __shfl_xor(s4, 2);
    if (h == 0) csp[rr] = u_l[rr] * s4;
  }
  __syncthreads();
  float rv = (t < NSP) ? csp[t] : 0.f;
  if (w < 4) {
    #pragma unroll
    for (int off = 32; off >= 1; off >>= 1) rv += __shfl_down(rv, off);
    if (l == 0) red[w] = rv;
  }
  __syncthreads();
  if (t == 0) out[p] = TEMP * (red[0] + red[1] + red[2] + red[3]);
}

extern "C" void kernel_launch(void* const* d_in, const int* in_sizes, int n_in,
                              void* d_out, int out_size, void* d_ws, size_t ws_size,
                              hipStream_t stream) {
  const float* x1 = (const float*)d_in[0];   // [200][640][196]
  const float* x2 = (const float*)d_in[1];   // [25][640][196]
  char* wsb = (char*)d_ws;
  float* out = (float*)d_out;
  bool qpre = ws_size >= WS_NEED_QPRE;

  hipMemsetAsync(wsb + B_SP, 0, 321440, stream);   // zero stat accumulators
  hipLaunchKernelGGL(k_proto, dim3(10, 5), dim3(256), 0, stream, x2, wsb);
  hipLaunchKernelGGL(k_qstats, dim3(10, 200), dim3(256), 0, stream, x1, wsb);
  hipLaunchKernelGGL(k_fin, dim3(157), dim3(256), 0, stream, wsb);
  hipLaunchKernelGGL(k_conv, dim3(20, 5), dim3(256), 0, stream,
                     (const float*)(wsb + B_PF32), (const float*)(wsb + B_MP),
                     (const float*)(wsb + B_RP), wsb + B_PF16);
  if (qpre)
    hipLaunchKernelGGL(k_conv, dim3(20, 200), dim3(256), 0, stream,
                       x1, (const float*)(wsb + B_MQ), (const float*)(wsb + B_RQ), wsb + B_QF16);
  hipLaunchKernelGGL(k_w1, dim3(MQ), dim3(256), 0, stream, x1, wsb);
  hipLaunchKernelGGL(k_w2, dim3(MQ), dim3(256), 0, stream, wsb);
  if (qpre)
    hipLaunchKernelGGL(k_pair<true>, dim3(MQ * WAYS), dim3(1024), PAIR_LDS, stream, x1, wsb, out);
  else
    hipLaunchKernelGGL(k_pair<false>, dim3(MQ * WAYS), dim3(1024), PAIR_LDS, stream, x1, wsb, out);
}

// Round 3
// 1158.905 us; speedup vs baseline: 3.8196x; 1.6177x over previous
//
#include <hip/hip_runtime.h>

// DeepEMD metric, round 3: symmetric 2-barrier Sinkhorn (no atomics, no partials),
// bank-conflict-free row/col passes, compile-time LDS offsets.

#define MQ 200
#define WAYS 5
#define SHOTS 5
#define CDIM 640
#define NSP 196
#define SPAD 208
#define ITERS 50

#define RCP_EPS_LOG2E 28.853900817779268f   // log2(e)/eps
#define EPS_LN2 0.034657359027997264f       // eps*ln(2)
#define TEMP 12.5f

// ---- workspace byte offsets ----
#define B_PF32 0u           // proto f32 [5][640][196]
#define B_PP   2508800u     // pooled_p [5][640]
#define B_PQ   2521600u     // pooled_q [200][640]
#define B_SP   3033600u     // accum: sum_p [5][196]
#define B_SP2  3037520u
#define B_SQ   3041440u     // accum: sum_q [200][196]
#define B_SQ2  3198240u
#define B_MP   3355040u
#define B_RP   3358960u
#define B_MQ   3362880u
#define B_RQ   3519680u
#define B_A    3676480u     // a marginals [200][5][196]
#define B_B    4460480u     // b marginals [200][5][196]
#define B_PF16 5244480u     // proto f16 staged [5][20][26624B]
#define B_QF16 7906880u     // query f16 staged [200][20][26624B]
#define KCB    26624u
#define ROWB   532480u      // 20*KCB
#define WS_NEED_QPRE 114402880ull

typedef _Float16 half8 __attribute__((ext_vector_type(8)));
typedef float f32x4 __attribute__((ext_vector_type(4)));

// LDS: Km 153664 | u 784 | v 784 | a 784 | b 784 | red 16
#define PAIR_LDS 156816

// ---------------- proto: shot-mean, pooled_p, channel-sum partials ----------------
__global__ __launch_bounds__(256) void k_proto(const float* __restrict__ x2, char* __restrict__ wsb) {
  float* pf32 = (float*)(wsb + B_PF32);
  float* pp   = (float*)(wsb + B_PP);
  float* sp   = (float*)(wsb + B_SP);
  float* sp2  = (float*)(wsb + B_SP2);
  __shared__ float ppl[64];
  int cg = blockIdx.x, wy = blockIdx.y, t = threadIdx.x, l = t & 63;
  if (t < 64) ppl[t] = 0.f;
  __syncthreads();
  int s = t; bool act = s < NSP;
  float as_ = 0.f, as2 = 0.f;
  int cb = cg * 64;
  for (int c = 0; c < 64; c++) {
    float p = 0.f;
    if (act) {
      const float* b0 = x2 + ((size_t)(wy * SHOTS) * CDIM + (cb + c)) * NSP + s;
      #pragma unroll
      for (int sh = 0; sh < SHOTS; sh++) p += b0[(size_t)sh * CDIM * NSP];
      p *= 0.2f;
      pf32[((size_t)wy * CDIM + cb + c) * NSP + s] = p;
      as_ += p; as2 += p * p;
    }
    float ps = p;
    #pragma unroll
    for (int off = 32; off >= 1; off >>= 1) ps += __shfl_xor(ps, off);
    if (l == 0) atomicAdd(&ppl[c], ps);
  }
  __syncthreads();
  if (act) { atomicAdd(&sp[wy * NSP + s], as_); atomicAdd(&sp2[wy * NSP + s], as2); }
  if (t < 64) pp[wy * CDIM + cb + t] = ppl[t] * (1.f / 196.f);
}

// ---------------- query: pooled_q, channel-sum partials ----------------
__global__ __launch_bounds__(256) void k_qstats(const float* __restrict__ x1, char* __restrict__ wsb) {
  float* pq  = (float*)(wsb + B_PQ);
  float* sq  = (float*)(wsb + B_SQ);
  float* sq2 = (float*)(wsb + B_SQ2);
  __shared__ float ppl[64];
  int cg = blockIdx.x, m = blockIdx.y, t = threadIdx.x, l = t & 63;
  if (t < 64) ppl[t] = 0.f;
  __syncthreads();
  int s = t; bool act = s < NSP;
  float as_ = 0.f, as2 = 0.f;
  int cb = cg * 64;
  const float* xb = x1 + (size_t)m * CDIM * NSP;
  for (int c = 0; c < 64; c++) {
    float p = 0.f;
    if (act) { p = xb[(size_t)(cb + c) * NSP + s]; as_ += p; as2 += p * p; }
    float ps = p;
    #pragma unroll
    for (int off = 32; off >= 1; off >>= 1) ps += __shfl_xor(ps, off);
    if (l == 0) atomicAdd(&ppl[c], ps);
  }
  __syncthreads();
  if (act) { atomicAdd(&sq[(size_t)m * NSP + s], as_); atomicAdd(&sq2[(size_t)m * NSP + s], as2); }
  if (t < 64) pq[(size_t)m * CDIM + cb + t] = ppl[t] * (1.f / 196.f);
}

// ---------------- finalize center/norm stats ----------------
__global__ __launch_bounds__(256) void k_fin(char* __restrict__ wsb) {
  int i = blockIdx.x * 256 + threadIdx.x;
  if (i < WAYS * NSP) {
    float sm = ((float*)(wsb + B_SP))[i], s2 = ((float*)(wsb + B_SP2))[i];
    float mean = sm * (1.f / CDIM);
    float var = s2 - CDIM * mean * mean;
    ((float*)(wsb + B_MP))[i] = mean;
    ((float*)(wsb + B_RP))[i] = 1.f / fmaxf(sqrtf(fmaxf(var, 0.f)), 1e-8f);
  } else if (i < WAYS * NSP + MQ * NSP) {
    int j = i - WAYS * NSP;
    float sm = ((float*)(wsb + B_SQ))[j], s2 = ((float*)(wsb + B_SQ2))[j];
    float mean = sm * (1.f / CDIM);
    float var = s2 - CDIM * mean * mean;
    ((float*)(wsb + B_MQ))[j] = mean;
    ((float*)(wsb + B_RQ))[j] = 1.f / fmaxf(sqrtf(fmaxf(var, 0.f)), 1e-8f);
  }
}

// ---------------- center+normalize -> f16 hi/lo in MFMA staging layout ----------------
__global__ __launch_bounds__(256) void k_conv(const float* __restrict__ src,
                                              const float* __restrict__ meanA,
                                              const float* __restrict__ rnA,
                                              char* __restrict__ dst) {
  int kc = blockIdx.x, rI = blockIdx.y, t = threadIdx.x;
  const float* s0 = src + (size_t)rI * CDIM * NSP;
  const float* me = meanA + (size_t)rI * NSP;
  const float* rn = rnA + (size_t)rI * NSP;
  _Float16* d = (_Float16*)(dst + (size_t)rI * ROWB + (size_t)kc * KCB);
  int s = t;
  if (s < SPAD) {
    bool ok = s < NSP;
    float mm = ok ? me[s] : 0.f, rr = ok ? rn[s] : 0.f;
    for (int kg = 0; kg < 4; kg++) {
      half8 hv{}, lv{};
      #pragma unroll
      for (int qq = 0; qq < 8; qq++) {
        float x = 0.f;
        if (ok) x = (s0[(size_t)(kc * 32 + kg * 8 + qq) * NSP + s] - mm) * rr;
        _Float16 h = (_Float16)x;
        hv[qq] = h; lv[qq] = (_Float16)(x - (float)h);
      }
      *(half8*)&d[(kg * SPAD + s) * 8] = hv;
      *(half8*)&d[6656 + (kg * SPAD + s) * 8] = lv;
    }
  }
}

// ---------------- query-side marginals ----------------
__global__ __launch_bounds__(256) void k_w1(const float* __restrict__ x1, char* __restrict__ wsb) {
  const float* pp = (const float*)(wsb + B_PP);
  float* A = (float*)(wsb + B_A);
  __shared__ float ppl[WAYS * CDIM];
  __shared__ float red[256];
  int m = blockIdx.x, t = threadIdx.x;
  for (int i = t; i < WAYS * CDIM; i += 256) ppl[i] = pp[i];
  __syncthreads();
  float acc[WAYS] = {0, 0, 0, 0, 0};
  const float* q = x1 + (size_t)m * CDIM * NSP;
  if (t < NSP) {
    for (int c = 0; c < CDIM; c++) {
      float qv = q[(size_t)c * NSP + t];
      #pragma unroll
      for (int n = 0; n < WAYS; n++) acc[n] += qv * ppl[n * CDIM + c];
    }
  }
  #pragma unroll
  for (int n = 0; n < WAYS; n++) {
    float wv = (t < NSP) ? (fmaxf(acc[n], 0.f) + 1e-3f) : 0.f;
    red[t] = wv;
    __syncthreads();
    for (int st = 128; st >= 1; st >>= 1) { if (t < st) red[t] += red[t + st]; __syncthreads(); }
    float sm = red[0];
    __syncthreads();
    if (t < NSP) A[((size_t)m * WAYS + n) * NSP + t] = wv / sm;
  }
}

// ---------------- proto-side marginals ----------------
__global__ __launch_bounds__(256) void k_w2(char* __restrict__ wsb) {
  const float* pf32 = (const float*)(wsb + B_PF32);
  const float* pq = (const float*)(wsb + B_PQ);
  float* B = (float*)(wsb + B_B);
  __shared__ float pql[CDIM];
  __shared__ float red[256];
  int m = blockIdx.x, t = threadIdx.x;
  for (int i = t; i < CDIM; i += 256) pql[i] = pq[(size_t)m * CDIM + i];
  __syncthreads();
  float acc[WAYS] = {0, 0, 0, 0, 0};
  if (t < NSP) {
    #pragma unroll
    for (int n = 0; n < WAYS; n++) {
      float a = 0.f;
      for (int c = 0; c < CDIM; c++) a += pf32[((size_t)n * CDIM + c) * NSP + t] * pql[c];
      acc[n] = a;
    }
  }
  #pragma unroll
  for (int n = 0; n < WAYS; n++) {
    float wv = (t < NSP) ? (fmaxf(acc[n], 0.f) + 1e-3f) : 0.f;
    red[t] = wv;
    __syncthreads();
    for (int st = 128; st >= 1; st >>= 1) { if (t < st) red[t] += red[t + st]; __syncthreads(); }
    float sm = red[0];
    __syncthreads();
    if (t < NSP) B[((size_t)m * WAYS + n) * NSP + t] = wv / sm;
  }
}

#define MFMA16(a, b, c) __builtin_amdgcn_mfma_f32_16x16x32_f16(a, b, c, 0, 0, 0)

// ---------------- fused pair kernel ----------------
template <bool QPRE>
__global__ __launch_bounds__(1024, 4) void k_pair(const float* __restrict__ x1,
                                                  char* __restrict__ wsb,
                                                  float* __restrict__ out) {
  extern __shared__ char smem[];
  float* Km = (float*)smem;                    // [196][196]
  float* u_l = (float*)(smem + 153664);
  float* v_l = u_l + NSP;
  float* a_l = v_l + NSP;
  float* b_l = a_l + NSP;
  float* red = (float*)(smem + 156800);        // 4 floats

  int p = blockIdx.x, m = p / WAYS, n = p % WAYS;
  int t = threadIdx.x, w = t >> 6, l = t & 63;
  int lid = l & 15, kg4 = l >> 4;
  int WR = w >> 2, WC = w & 3;

  // P0
  if (t < NSP) {
    a_l[t] = ((const float*)(wsb + B_A))[((size_t)m * WAYS + n) * NSP + t];
    b_l[t] = ((const float*)(wsb + B_B))[((size_t)m * WAYS + n) * NSP + t];
    v_l[t] = 1.f;
  }
  __syncthreads();

  const char* srcQ = wsb + B_QF16 + (size_t)m * ROWB;
  const char* srcP = wsb + B_PF16 + (size_t)n * ROWB;

  f32x4 acc[4][4];
  #pragma unroll
  for (int qi = 0; qi < 4; qi++)
    #pragma unroll
    for (int r = 0; r < 4; r++)
      #pragma unroll
      for (int e = 0; e < 4; e++) acc[qi][r][e] = 0.f;

  f32x4 st0, st1, st2, st3;

  auto STAGE_LOAD = [&](int kc) {
    if constexpr (QPRE) {
      const char* q0 = srcQ + (size_t)kc * KCB;
      const char* p0 = srcP + (size_t)kc * KCB;
      st0 = *(const f32x4*)(q0 + (size_t)t * 16);
      st1 = (t < 640) ? *(const f32x4*)(q0 + (size_t)(1024 + t) * 16)
                      : *(const f32x4*)(p0 + (size_t)(t - 640) * 16);
      st2 = *(const f32x4*)(p0 + (size_t)(384 + t) * 16);
      if (t < 256) st3 = *(const f32x4*)(p0 + (size_t)(1408 + t) * 16);
    } else {
      int kg = t >> 8, s = t & 255;
      half8 hv{}, lv{};
      if (s < SPAD) {
        bool ok = s < NSP;
        float mm = ok ? ((const float*)(wsb + B_MQ))[(size_t)m * NSP + s] : 0.f;
        float rr = ok ? ((const float*)(wsb + B_RQ))[(size_t)m * NSP + s] : 0.f;
        #pragma unroll
        for (int qq = 0; qq < 8; qq++) {
          float x = 0.f;
          if (ok) x = (x1[((size_t)m * CDIM + kc * 32 + kg * 8 + qq) * NSP + s] - mm) * rr;
          _Float16 h = (_Float16)x;
          hv[qq] = h; lv[qq] = (_Float16)(x - (float)h);
        }
      }
      st0 = __builtin_bit_cast(f32x4, hv);
      st1 = __builtin_bit_cast(f32x4, lv);
      const char* p0 = srcP + (size_t)kc * KCB;
      st2 = *(const f32x4*)(p0 + (size_t)t * 16);
      if (t < 640) st3 = *(const f32x4*)(p0 + (size_t)(1024 + t) * 16);
    }
  };
  auto STAGE_WRITE = [&](char* bufc) {
    if constexpr (QPRE) {
      *(f32x4*)(bufc + (size_t)t * 16) = st0;
      *(f32x4*)(bufc + (size_t)(1024 + t) * 16) = st1;
      *(f32x4*)(bufc + (size_t)(2048 + t) * 16) = st2;
      if (t < 256) *(f32x4*)(bufc + (size_t)(3072 + t) * 16) = st3;
    } else {
      int kg = t >> 8, s = t & 255;
      if (s < SPAD) {
        *(f32x4*)(bufc + (size_t)(kg * SPAD + s) * 16) = st0;
        *(f32x4*)(bufc + 13312 + (size_t)(kg * SPAD + s) * 16) = st1;
      }
      *(f32x4*)(bufc + 26624 + (size_t)t * 16) = st2;
      if (t < 640) *(f32x4*)(bufc + 26624 + (size_t)(1024 + t) * 16) = st3;
    }
  };

  // ---- GEMM: 20 K-chunks, double-buffered staging, 1 barrier per chunk
  int buf = 0;
  STAGE_LOAD(0);
  STAGE_WRITE(smem);
  __syncthreads();
  for (int kc = 0; kc < 20; kc++) {
    char* cur = smem + (size_t)buf * 53248;
    char* nxt = smem + (size_t)(buf ^ 1) * 53248;
    if (kc < 19) STAGE_LOAD(kc + 1);
    const _Float16* Ah = (const _Float16*)cur;
    const _Float16* Al = (const _Float16*)(cur + 13312);
    const _Float16* Bh = (const _Float16*)(cur + 26624);
    const _Float16* Bl = (const _Float16*)(cur + 39936);
    half8 ah[4], al[4];
    #pragma unroll
    for (int qi = 0; qi < 4; qi++) {
      int tt = WR + 4 * qi;
      if (tt < 13) {
        ah[qi] = *(const half8*)&Ah[((size_t)kg4 * SPAD + tt * 16 + lid) * 8];
        al[qi] = *(const half8*)&Al[((size_t)kg4 * SPAD + tt * 16 + lid) * 8];
      }
    }
    #pragma unroll
    for (int r = 0; r < 4; r++) {
      int jt = WC + 4 * r;
      if (jt < 13) {
        half8 bh = *(const half8*)&Bh[((size_t)kg4 * SPAD + jt * 16 + lid) * 8];
        half8 bl = *(const half8*)&Bl[((size_t)kg4 * SPAD + jt * 16 + lid) * 8];
        #pragma unroll
        for (int qi = 0; qi < 4; qi++) {
          int tt = WR + 4 * qi;
          if (tt < 13) {
            acc[qi][r] = MFMA16(ah[qi], bh, acc[qi][r]);
            acc[qi][r] = MFMA16(ah[qi], bl, acc[qi][r]);
            acc[qi][r] = MFMA16(al[qi], bh, acc[qi][r]);
          }
        }
      }
    }
    if (kc < 19) STAGE_WRITE(nxt);
    __syncthreads();
    buf ^= 1;
  }

  // ---- P2: K = exp((sim-1)/eps) into LDS
  #pragma unroll
  for (int qi = 0; qi < 4; qi++) {
    int tt = WR + 4 * qi;
    if (tt < 13) {
      #pragma unroll
      for (int r = 0; r < 4; r++) {
        int jt = WC + 4 * r;
        if (jt < 13) {
          int j = jt * 16 + lid;
          if (j < NSP) {
            #pragma unroll
            for (int e = 0; e < 4; e++) {
              int i = tt * 16 + kg4 * 4 + e;
              if (i < NSP) Km[(size_t)i * NSP + j] = exp2f((acc[qi][r][e] - 1.f) * RCP_EPS_LOG2E);
            }
          }
        }
      }
    }
  }
  __syncthreads();

  // ---- P3: Sinkhorn, symmetric 2-barrier form
  int idx = t >> 2, hh = t & 3;          // row/col index + quarter-lane
  bool act = t < 784;
  const int cb48 = 48 * hh;               // row pass: column chunk {48,48,48,52}
  for (int it = 0; it < ITERS; it++) {
    // row pass: u = a / (K v)
    if (act) {
      const f32x4* KmR = (const f32x4*)(Km + (size_t)idx * NSP + cb48);
      const f32x4* vR  = (const f32x4*)(v_l + cb48);
      float rs = 0.f;
      #pragma unroll
      for (int kb = 0; kb < 12; kb++) {
        f32x4 k4 = KmR[kb], v4 = vR[kb];
        rs += k4[0] * v4[0] + k4[1] * v4[1] + k4[2] * v4[2] + k4[3] * v4[3];
      }
      if (hh == 3) {
        f32x4 k4 = KmR[12], v4 = vR[12];
        rs += k4[0] * v4[0] + k4[1] * v4[1] + k4[2] * v4[2] + k4[3] * v4[3];
      }
      rs += __shfl_xor(rs, 1);
      rs += __shfl_xor(rs, 2);
      if (hh == 0) u_l[idx] = a_l[idx] / fmaxf(rs, 1e-35f);
    }
    __syncthreads();
    // col pass: v = b / (K^T u); rows {8k+2hh, 8k+2hh+1} -> 2 lanes/bank (free)
    if (act) {
      const float* KmC = Km + idx;
      const float2* u2p = (const float2*)u_l;
      float cs = 0.f;
      #pragma unroll
      for (int k = 0; k < 24; k++) {
        float2 u2 = u2p[4 * k + hh];
        cs += KmC[(size_t)(8 * k + 2 * hh) * NSP] * u2.x;
        cs += KmC[(size_t)(8 * k + 2 * hh + 1) * NSP] * u2.y;
      }
      if (hh < 2) {
        float2 u2 = u2p[96 + hh];
        cs += KmC[(size_t)(192 + 2 * hh) * NSP] * u2.x;
        cs += KmC[(size_t)(193 + 2 * hh) * NSP] * u2.y;
      }
      cs += __shfl_xor(cs, 1);
      cs += __shfl_xor(cs, 2);
      if (hh == 0) v_l[idx] = b_l[idx] / fmaxf(cs, 1e-35f);
    }
    __syncthreads();
  }

  // ---- P4: logits = temp * sum_ij sim * u_i K_ij v_j (sim from log2(K)); a_l as scratch
  if (act) {
    float s4 = 0.f;
    for (int jb = hh; jb < 49; jb += 4) {
      f32x4 k4 = *(const f32x4*)&Km[(size_t)idx * NSP + jb * 4];
      f32x4 v4 = *(const f32x4*)&v_l[jb * 4];
      #pragma unroll
      for (int qq = 0; qq < 4; qq++) {
        float kk = k4[qq];
        float sim = 1.f + EPS_LN2 * log2f(kk);
        s4 += sim * kk * v4[qq];
      }
    }
    s4 += __shfl_xor(s4, 1);
    s4 += __shfl_xor(s4, 2);
    if (hh == 0) a_l[idx] = u_l[idx] * s4;
  }
  __syncthreads();
  float rv = (t < NSP) ? a_l[t] : 0.f;
  if (w < 4) {
    #pragma unroll
    for (int off = 32; off >= 1; off >>= 1) rv += __shfl_down(rv, off);
    if (l == 0) red[w] = rv;
  }
  __syncthreads();
  if (t == 0) out[p] = TEMP * (red[0] + red[1] + red[2] + red[3]);
}

extern "C" void kernel_launch(void* const* d_in, const int* in_sizes, int n_in,
                              void* d_out, int out_size, void* d_ws, size_t ws_size,
                              hipStream_t stream) {
  const float* x1 = (const float*)d_in[0];   // [200][640][196]
  const float* x2 = (const float*)d_in[1];   // [25][640][196]
  char* wsb = (char*)d_ws;
  float* out = (float*)d_out;
  bool qpre = ws_size >= WS_NEED_QPRE;

  hipMemsetAsync(wsb + B_SP, 0, 321440, stream);   // zero stat accumulators
  hipLaunchKernelGGL(k_proto, dim3(10, 5), dim3(256), 0, stream, x2, wsb);
  hipLaunchKernelGGL(k_qstats, dim3(10, 200), dim3(256), 0, stream, x1, wsb);
  hipLaunchKernelGGL(k_fin, dim3(157), dim3(256), 0, stream, wsb);
  hipLaunchKernelGGL(k_conv, dim3(20, 5), dim3(256), 0, stream,
                     (const float*)(wsb + B_PF32), (const float*)(wsb + B_MP),
                     (const float*)(wsb + B_RP), wsb + B_PF16);
  if (qpre)
    hipLaunchKernelGGL(k_conv, dim3(20, 200), dim3(256), 0, stream,
                       x1, (const float*)(wsb + B_MQ), (const float*)(wsb + B_RQ), wsb + B_QF16);
  hipLaunchKernelGGL(k_w1, dim3(MQ), dim3(256), 0, stream, x1, wsb);
  hipLaunchKernelGGL(k_w2, dim3(MQ), dim3(256), 0, stream, wsb);
  if (qpre)
    hipLaunchKernelGGL(k_pair<true>, dim3(MQ * WAYS), dim3(1024), PAIR_LDS, stream, x1, wsb, out);
  else
    hipLaunchKernelGGL(k_pair<false>, dim3(MQ * WAYS), dim3(1024), PAIR_LDS, stream, x1, wsb, out);
}

// Round 6
// 1006.421 us; speedup vs baseline: 4.3983x; 1.1515x over previous
//
#include <hip/hip_runtime.h>

// DeepEMD metric, round 5: register-resident Sinkhorn — FIXED chunk partition
// ({48,48,48,52} guard k<12||hh==3; round-4 guard double-counted 12 columns).

#define MQ 200
#define WAYS 5
#define SHOTS 5
#define CDIM 640
#define NSP 196
#define SPAD 208
#define ITERS 50

#define RCP_EPS_LOG2E 28.853900817779268f   // log2(e)/eps
#define EPS_LN2 0.034657359027997264f       // eps*ln(2)
#define TEMP 12.5f

// ---- workspace byte offsets ----
#define B_PF32 0u           // proto f32 [5][640][196]
#define B_PP   2508800u     // pooled_p [5][640]
#define B_PQ   2521600u     // pooled_q [200][640]
#define B_SP   3033600u     // accum: sum_p [5][196]
#define B_SP2  3037520u
#define B_SQ   3041440u     // accum: sum_q [200][196]
#define B_SQ2  3198240u
#define B_MP   3355040u
#define B_RP   3358960u
#define B_MQ   3362880u
#define B_RQ   3519680u
#define B_A    3676480u     // a marginals [200][5][196] (accum then in-place final)
#define B_B    4460480u     // b marginals [200][5][196] (accum then in-place final)
#define B_PF16 5244480u     // proto f16 staged [5][20][26624B]
#define B_QF16 7906880u     // query f16 staged [200][20][26624B]
#define KCB    26624u
#define ROWB   532480u      // 20*KCB
#define WS_NEED_QPRE 114402880ull

typedef _Float16 half8 __attribute__((ext_vector_type(8)));
typedef float f32x4 __attribute__((ext_vector_type(4)));

// LDS: Km 153664 | u 784 | v 784 | a 784 | b 784 | red 16
#define PAIR_LDS 156816

// ---------------- proto: shot-mean, pooled_p, channel-sum partials ----------------
__global__ __launch_bounds__(256) void k_proto(const float* __restrict__ x2, char* __restrict__ wsb) {
  float* pf32 = (float*)(wsb + B_PF32);
  float* pp   = (float*)(wsb + B_PP);
  float* sp   = (float*)(wsb + B_SP);
  float* sp2  = (float*)(wsb + B_SP2);
  __shared__ float ppl[64];
  int cg = blockIdx.x, wy = blockIdx.y, t = threadIdx.x, l = t & 63;
  if (t < 64) ppl[t] = 0.f;
  __syncthreads();
  int s = t; bool act = s < NSP;
  float as_ = 0.f, as2 = 0.f;
  int cb = cg * 64;
  for (int c = 0; c < 64; c++) {
    float p = 0.f;
    if (act) {
      const float* b0 = x2 + ((size_t)(wy * SHOTS) * CDIM + (cb + c)) * NSP + s;
      #pragma unroll
      for (int sh = 0; sh < SHOTS; sh++) p += b0[(size_t)sh * CDIM * NSP];
      p *= 0.2f;
      pf32[((size_t)wy * CDIM + cb + c) * NSP + s] = p;
      as_ += p; as2 += p * p;
    }
    float ps = p;
    #pragma unroll
    for (int off = 32; off >= 1; off >>= 1) ps += __shfl_xor(ps, off);
    if (l == 0) atomicAdd(&ppl[c], ps);
  }
  __syncthreads();
  if (act) { atomicAdd(&sp[wy * NSP + s], as_); atomicAdd(&sp2[wy * NSP + s], as2); }
  if (t < 64) pp[wy * CDIM + cb + t] = ppl[t] * (1.f / 196.f);
}

// ---------------- query: pooled_q, channel sums, a-marginal partials ----------------
__global__ __launch_bounds__(256) void k_qstats(const float* __restrict__ x1, char* __restrict__ wsb) {
  float* pq  = (float*)(wsb + B_PQ);
  float* sq  = (float*)(wsb + B_SQ);
  float* sq2 = (float*)(wsb + B_SQ2);
  float* accA = (float*)(wsb + B_A);
  const float* pp = (const float*)(wsb + B_PP);
  __shared__ float ppl[64];
  __shared__ float ppl2[WAYS * 64];
  int cg = blockIdx.x, m = blockIdx.y, t = threadIdx.x, l = t & 63;
  int cb = cg * 64;
  if (t < 64) ppl[t] = 0.f;
  for (int i = t; i < WAYS * 64; i += 256) ppl2[i] = pp[(i >> 6) * CDIM + cb + (i & 63)];
  __syncthreads();
  int s = t; bool act = s < NSP;
  float as_ = 0.f, as2 = 0.f;
  float aacc[WAYS] = {0, 0, 0, 0, 0};
  const float* xb = x1 + (size_t)m * CDIM * NSP;
  for (int c = 0; c < 64; c++) {
    float p = 0.f;
    if (act) {
      p = xb[(size_t)(cb + c) * NSP + s];
      as_ += p; as2 += p * p;
      #pragma unroll
      for (int n = 0; n < WAYS; n++) aacc[n] += p * ppl2[n * 64 + c];
    }
    float ps = p;
    #pragma unroll
    for (int off = 32; off >= 1; off >>= 1) ps += __shfl_xor(ps, off);
    if (l == 0) atomicAdd(&ppl[c], ps);
  }
  __syncthreads();
  if (act) {
    atomicAdd(&sq[(size_t)m * NSP + s], as_);
    atomicAdd(&sq2[(size_t)m * NSP + s], as2);
    #pragma unroll
    for (int n = 0; n < WAYS; n++)
      atomicAdd(&accA[((size_t)m * WAYS + n) * NSP + s], aacc[n]);
  }
  if (t < 64) pq[(size_t)m * CDIM + cb + t] = ppl[t] * (1.f / 196.f);
}

// ---------------- b-marginal partials: proto x pooled_q ----------------
__global__ __launch_bounds__(256) void k_w2p(char* __restrict__ wsb) {
  const float* pf32 = (const float*)(wsb + B_PF32);
  const float* pq = (const float*)(wsb + B_PQ);
  float* accB = (float*)(wsb + B_B);
  __shared__ float pql[64];
  int cg = blockIdx.x, m = blockIdx.y, t = threadIdx.x;
  int cb = cg * 64;
  if (t < 64) pql[t] = pq[(size_t)m * CDIM + cb + t];
  __syncthreads();
  if (t < NSP) {
    float bacc[WAYS] = {0, 0, 0, 0, 0};
    for (int c = 0; c < 64; c++) {
      float pv = pql[c];
      #pragma unroll
      for (int n = 0; n < WAYS; n++)
        bacc[n] += pf32[((size_t)n * CDIM + cb + c) * NSP + t] * pv;
    }
    #pragma unroll
    for (int n = 0; n < WAYS; n++)
      atomicAdd(&accB[((size_t)m * WAYS + n) * NSP + t], bacc[n]);
  }
}

// ---------------- finalize center/norm stats ----------------
__global__ __launch_bounds__(256) void k_fin(char* __restrict__ wsb) {
  int i = blockIdx.x * 256 + threadIdx.x;
  if (i < WAYS * NSP) {
    float sm = ((float*)(wsb + B_SP))[i], s2 = ((float*)(wsb + B_SP2))[i];
    float mean = sm * (1.f / CDIM);
    float var = s2 - CDIM * mean * mean;
    ((float*)(wsb + B_MP))[i] = mean;
    ((float*)(wsb + B_RP))[i] = 1.f / fmaxf(sqrtf(fmaxf(var, 0.f)), 1e-8f);
  } else if (i < WAYS * NSP + MQ * NSP) {
    int j = i - WAYS * NSP;
    float sm = ((float*)(wsb + B_SQ))[j], s2 = ((float*)(wsb + B_SQ2))[j];
    float mean = sm * (1.f / CDIM);
    float var = s2 - CDIM * mean * mean;
    ((float*)(wsb + B_MQ))[j] = mean;
    ((float*)(wsb + B_RQ))[j] = 1.f / fmaxf(sqrtf(fmaxf(var, 0.f)), 1e-8f);
  }
}

// ---------------- finalize marginals: relu + 1e-3, normalize (in place) ----------------
__global__ __launch_bounds__(256) void k_finm(char* __restrict__ wsb) {
  float* A = (float*)(wsb + B_A);
  float* B = (float*)(wsb + B_B);
  __shared__ float red[256];
  int p = blockIdx.x, t = threadIdx.x;
  float av = (t < NSP) ? (fmaxf(A[(size_t)p * NSP + t], 0.f) + 1e-3f) : 0.f;
  red[t] = av;
  __syncthreads();
  for (int st = 128; st >= 1; st >>= 1) { if (t < st) red[t] += red[t + st]; __syncthreads(); }
  float sa = red[0];
  __syncthreads();
  if (t < NSP) A[(size_t)p * NSP + t] = av / sa;
  float bv = (t < NSP) ? (fmaxf(B[(size_t)p * NSP + t], 0.f) + 1e-3f) : 0.f;
  red[t] = bv;
  __syncthreads();
  for (int st = 128; st >= 1; st >>= 1) { if (t < st) red[t] += red[t + st]; __syncthreads(); }
  float sb = red[0];
  __syncthreads();
  if (t < NSP) B[(size_t)p * NSP + t] = bv / sb;
}

// ---------------- center+normalize -> f16 hi/lo in MFMA staging layout ----------------
__global__ __launch_bounds__(256) void k_conv(const float* __restrict__ src,
                                              const float* __restrict__ meanA,
                                              const float* __restrict__ rnA,
                                              char* __restrict__ dst) {
  int kc = blockIdx.x, rI = blockIdx.y, t = threadIdx.x;
  const float* s0 = src + (size_t)rI * CDIM * NSP;
  const float* me = meanA + (size_t)rI * NSP;
  const float* rn = rnA + (size_t)rI * NSP;
  _Float16* d = (_Float16*)(dst + (size_t)rI * ROWB + (size_t)kc * KCB);
  int s = t;
  if (s < SPAD) {
    bool ok = s < NSP;
    float mm = ok ? me[s] : 0.f, rr = ok ? rn[s] : 0.f;
    for (int kg = 0; kg < 4; kg++) {
      half8 hv{}, lv{};
      #pragma unroll
      for (int qq = 0; qq < 8; qq++) {
        float x = 0.f;
        if (ok) x = (s0[(size_t)(kc * 32 + kg * 8 + qq) * NSP + s] - mm) * rr;
        _Float16 h = (_Float16)x;
        hv[qq] = h; lv[qq] = (_Float16)(x - (float)h);
      }
      *(half8*)&d[(kg * SPAD + s) * 8] = hv;
      *(half8*)&d[6656 + (kg * SPAD + s) * 8] = lv;
    }
  }
}

#define MFMA16(a, b, c) __builtin_amdgcn_mfma_f32_16x16x32_f16(a, b, c, 0, 0, 0)

// ---------------- fused pair kernel ----------------
template <bool QPRE>
__global__ __launch_bounds__(1024, 4) void k_pair(const float* __restrict__ x1,
                                                  char* __restrict__ wsb,
                                                  float* __restrict__ out) {
  extern __shared__ char smem[];
  float* Km = (float*)smem;                    // [196][196]
  float* u_l = (float*)(smem + 153664);
  float* v_l = u_l + NSP;
  float* a_l = v_l + NSP;
  float* b_l = a_l + NSP;
  float* red = (float*)(smem + 156800);        // 4 floats

  int p = blockIdx.x, m = p / WAYS, n = p % WAYS;
  int t = threadIdx.x, w = t >> 6, l = t & 63;
  int lid = l & 15, kg4 = l >> 4;
  int WR = w >> 2, WC = w & 3;

  // P0
  if (t < NSP) {
    a_l[t] = ((const float*)(wsb + B_A))[((size_t)m * WAYS + n) * NSP + t];
    b_l[t] = ((const float*)(wsb + B_B))[((size_t)m * WAYS + n) * NSP + t];
    v_l[t] = 1.f;
  }
  __syncthreads();

  const char* srcQ = wsb + B_QF16 + (size_t)m * ROWB;
  const char* srcP = wsb + B_PF16 + (size_t)n * ROWB;

  {
    f32x4 acc[4][4];
    #pragma unroll
    for (int qi = 0; qi < 4; qi++)
      #pragma unroll
      for (int r = 0; r < 4; r++)
        #pragma unroll
        for (int e = 0; e < 4; e++) acc[qi][r][e] = 0.f;

    f32x4 st0, st1, st2, st3;

    auto STAGE_LOAD = [&](int kc) {
      if constexpr (QPRE) {
        const char* q0 = srcQ + (size_t)kc * KCB;
        const char* p0 = srcP + (size_t)kc * KCB;
        st0 = *(const f32x4*)(q0 + (size_t)t * 16);
        st1 = (t < 640) ? *(const f32x4*)(q0 + (size_t)(1024 + t) * 16)
                        : *(const f32x4*)(p0 + (size_t)(t - 640) * 16);
        st2 = *(const f32x4*)(p0 + (size_t)(384 + t) * 16);
        if (t < 256) st3 = *(const f32x4*)(p0 + (size_t)(1408 + t) * 16);
      } else {
        int kg = t >> 8, s = t & 255;
        half8 hv{}, lv{};
        if (s < SPAD) {
          bool ok = s < NSP;
          float mm = ok ? ((const float*)(wsb + B_MQ))[(size_t)m * NSP + s] : 0.f;
          float rr = ok ? ((const float*)(wsb + B_RQ))[(size_t)m * NSP + s] : 0.f;
          #pragma unroll
          for (int qq = 0; qq < 8; qq++) {
            float x = 0.f;
            if (ok) x = (x1[((size_t)m * CDIM + kc * 32 + kg * 8 + qq) * NSP + s] - mm) * rr;
            _Float16 h = (_Float16)x;
            hv[qq] = h; lv[qq] = (_Float16)(x - (float)h);
          }
        }
        st0 = __builtin_bit_cast(f32x4, hv);
        st1 = __builtin_bit_cast(f32x4, lv);
        const char* p0 = srcP + (size_t)kc * KCB;
        st2 = *(const f32x4*)(p0 + (size_t)t * 16);
        if (t < 640) st3 = *(const f32x4*)(p0 + (size_t)(1024 + t) * 16);
      }
    };
    auto STAGE_WRITE = [&](char* bufc) {
      if constexpr (QPRE) {
        *(f32x4*)(bufc + (size_t)t * 16) = st0;
        *(f32x4*)(bufc + (size_t)(1024 + t) * 16) = st1;
        *(f32x4*)(bufc + (size_t)(2048 + t) * 16) = st2;
        if (t < 256) *(f32x4*)(bufc + (size_t)(3072 + t) * 16) = st3;
      } else {
        int kg = t >> 8, s = t & 255;
        if (s < SPAD) {
          *(f32x4*)(bufc + (size_t)(kg * SPAD + s) * 16) = st0;
          *(f32x4*)(bufc + 13312 + (size_t)(kg * SPAD + s) * 16) = st1;
        }
        *(f32x4*)(bufc + 26624 + (size_t)t * 16) = st2;
        if (t < 640) *(f32x4*)(bufc + 26624 + (size_t)(1024 + t) * 16) = st3;
      }
    };

    // ---- GEMM: 20 K-chunks, double-buffered staging
    int buf = 0;
    STAGE_LOAD(0);
    STAGE_WRITE(smem);
    __syncthreads();
    for (int kc = 0; kc < 20; kc++) {
      char* cur = smem + (size_t)buf * 53248;
      char* nxt = smem + (size_t)(buf ^ 1) * 53248;
      if (kc < 19) STAGE_LOAD(kc + 1);
      const _Float16* Ah = (const _Float16*)cur;
      const _Float16* Al = (const _Float16*)(cur + 13312);
      const _Float16* Bh = (const _Float16*)(cur + 26624);
      const _Float16* Bl = (const _Float16*)(cur + 39936);
      half8 ah[4], al[4];
      #pragma unroll
      for (int qi = 0; qi < 4; qi++) {
        int tt = WR + 4 * qi;
        if (tt < 13) {
          ah[qi] = *(const half8*)&Ah[((size_t)kg4 * SPAD + tt * 16 + lid) * 8];
          al[qi] = *(const half8*)&Al[((size_t)kg4 * SPAD + tt * 16 + lid) * 8];
        }
      }
      #pragma unroll
      for (int r = 0; r < 4; r++) {
        int jt = WC + 4 * r;
        if (jt < 13) {
          half8 bh = *(const half8*)&Bh[((size_t)kg4 * SPAD + jt * 16 + lid) * 8];
          half8 bl = *(const half8*)&Bl[((size_t)kg4 * SPAD + jt * 16 + lid) * 8];
          #pragma unroll
          for (int qi = 0; qi < 4; qi++) {
            int tt = WR + 4 * qi;
            if (tt < 13) {
              acc[qi][r] = MFMA16(ah[qi], bh, acc[qi][r]);
              acc[qi][r] = MFMA16(ah[qi], bl, acc[qi][r]);
              acc[qi][r] = MFMA16(al[qi], bh, acc[qi][r]);
            }
          }
        }
      }
      if (kc < 19) STAGE_WRITE(nxt);
      __syncthreads();
      buf ^= 1;
    }

    // ---- P2: K = exp((sim-1)/eps) into LDS
    #pragma unroll
    for (int qi = 0; qi < 4; qi++) {
      int tt = WR + 4 * qi;
      if (tt < 13) {
        #pragma unroll
        for (int r = 0; r < 4; r++) {
          int jt = WC + 4 * r;
          if (jt < 13) {
            int j = jt * 16 + lid;
            if (j < NSP) {
              #pragma unroll
              for (int e = 0; e < 4; e++) {
                int i = tt * 16 + kg4 * 4 + e;
                if (i < NSP) Km[(size_t)i * NSP + j] = exp2f((acc[qi][r][e] - 1.f) * RCP_EPS_LOG2E);
              }
            }
          }
        }
      }
    }
  }
  __syncthreads();

  // ---- load K row-chunk and col-chunk into registers
  // Partition of 196 cols across hh: {48,48,48,52} -> chunk k active iff k<12 || hh==3
  int idx = t >> 2, hh = t & 3;
  bool act = t < 784;
  const int cb = 48 * hh;
  f32x4 Krow[13], Kcol[13];
  if (act) {
    #pragma unroll
    for (int k = 0; k < 13; k++) {
      if (k < 12 || hh == 3) {
        Krow[k] = *(const f32x4*)&Km[(size_t)idx * NSP + cb + 4 * k];
        #pragma unroll
        for (int e = 0; e < 4; e++)
          Kcol[k][e] = Km[(size_t)(cb + 4 * k + e) * NSP + idx];
      }
    }
  }

  // ---- P3: Sinkhorn, registers + broadcast vectors
  for (int it = 0; it < ITERS; it++) {
    if (act) {
      float rs = 0.f;
      #pragma unroll
      for (int k = 0; k < 13; k++) {
        if (k < 12 || hh == 3) {
          f32x4 v4 = *(const f32x4*)&v_l[cb + 4 * k];
          rs += Krow[k][0] * v4[0] + Krow[k][1] * v4[1] + Krow[k][2] * v4[2] + Krow[k][3] * v4[3];
        }
      }
      rs += __shfl_xor(rs, 1);
      rs += __shfl_xor(rs, 2);
      if (hh == 0) u_l[idx] = a_l[idx] / fmaxf(rs, 1e-35f);
    }
    __syncthreads();
    if (act) {
      float cs = 0.f;
      #pragma unroll
      for (int k = 0; k < 13; k++) {
        if (k < 12 || hh == 3) {
          f32x4 u4 = *(const f32x4*)&u_l[cb + 4 * k];
          cs += Kcol[k][0] * u4[0] + Kcol[k][1] * u4[1] + Kcol[k][2] * u4[2] + Kcol[k][3] * u4[3];
        }
      }
      cs += __shfl_xor(cs, 1);
      cs += __shfl_xor(cs, 2);
      if (hh == 0) v_l[idx] = b_l[idx] / fmaxf(cs, 1e-35f);
    }
    __syncthreads();
  }

  // ---- P4: logits from registers (sim recovered via log2(K)); a_l as scratch
  if (act) {
    float s4 = 0.f;
    #pragma unroll
    for (int k = 0; k < 13; k++) {
      if (k < 12 || hh == 3) {
        f32x4 v4 = *(const f32x4*)&v_l[cb + 4 * k];
        #pragma unroll
        for (int e = 0; e < 4; e++) {
          float kk = Krow[k][e];
          float sim = 1.f + EPS_LN2 * log2f(kk);
          s4 += sim * kk * v4[e];
        }
      }
    }
    s4 += __shfl_xor(s4, 1);
    s4 += __shfl_xor(s4, 2);
    if (hh == 0) a_l[idx] = u_l[idx] * s4;
  }
  __syncthreads();
  float rv = (t < NSP) ? a_l[t] : 0.f;
  if (w < 4) {
    #pragma unroll
    for (int off = 32; off >= 1; off >>= 1) rv += __shfl_down(rv, off);
    if (l == 0) red[w] = rv;
  }
  __syncthreads();
  if (t == 0) out[p] = TEMP * (red[0] + red[1] + red[2] + red[3]);
}

extern "C" void kernel_launch(void* const* d_in, const int* in_sizes, int n_in,
                              void* d_out, int out_size, void* d_ws, size_t ws_size,
                              hipStream_t stream) {
  const float* x1 = (const float*)d_in[0];   // [200][640][196]
  const float* x2 = (const float*)d_in[1];   // [25][640][196]
  char* wsb = (char*)d_ws;
  float* out = (float*)d_out;
  bool qpre = ws_size >= WS_NEED_QPRE;

  hipMemsetAsync(wsb + B_SP, 0, 321440, stream);     // stat accumulators
  hipMemsetAsync(wsb + B_A, 0, 1568000, stream);     // marginal accumulators
  hipLaunchKernelGGL(k_proto, dim3(10, 5), dim3(256), 0, stream, x2, wsb);
  hipLaunchKernelGGL(k_qstats, dim3(10, 200), dim3(256), 0, stream, x1, wsb);
  hipLaunchKernelGGL(k_w2p, dim3(10, 200), dim3(256), 0, stream, wsb);
  hipLaunchKernelGGL(k_fin, dim3(157), dim3(256), 0, stream, wsb);
  hipLaunchKernelGGL(k_finm, dim3(MQ * WAYS), dim3(256), 0, stream, wsb);
  hipLaunchKernelGGL(k_conv, dim3(20, 5), dim3(256), 0, stream,
                     (const float*)(wsb + B_PF32), (const float*)(wsb + B_MP),
                     (const float*)(wsb + B_RP), wsb + B_PF16);
  if (qpre)
    hipLaunchKernelGGL(k_conv, dim3(20, 200), dim3(256), 0, stream,
                       x1, (const float*)(wsb + B_MQ), (const float*)(wsb + B_RQ), wsb + B_QF16);
  if (qpre)
    hipLaunchKernelGGL(k_pair<true>, dim3(MQ * WAYS), dim3(1024), PAIR_LDS, stream, x1, wsb, out);
  else
    hipLaunchKernelGGL(k_pair<false>, dim3(MQ * WAYS), dim3(1024), PAIR_LDS, stream, x1, wsb, out);
}